// Round 9
// baseline (760.805 us; speedup 1.0000x reference)
//
#include <hip/hip_runtime.h>
#include <hip/hip_bf16.h>

#define B_ 64
#define L_ 1024
#define D_ 256
#define M_ (B_*L_)

typedef __attribute__((ext_vector_type(8))) short s16x8;
typedef __attribute__((ext_vector_type(4))) float f32x4;

__device__ __forceinline__ float sigmoidf_(float z) { return 1.0f/(1.0f + __expf(-z)); }

__device__ __forceinline__ unsigned short f2bf(float x) {
  unsigned int u = __builtin_bit_cast(unsigned int, x);
  u += 0x7fffu + ((u >> 16) & 1u);          // RNE
  return (unsigned short)(u >> 16);
}
__device__ __forceinline__ float bf2f(unsigned short u) {
  unsigned int x = ((unsigned int)u) << 16;
  return __builtin_bit_cast(float, x);
}
__device__ __forceinline__ uint4 pack8(const float* f) {
  union { unsigned short u[8]; uint4 v; } r;
  #pragma unroll
  for (int i = 0; i < 8; ++i) r.u[i] = f2bf(f[i]);
  return r.v;
}

// ---------------- K1: gather+convert+transpose -----------------------------
__global__ __launch_bounds__(256) void k_embedT(const int* __restrict__ qs,
    const float* __restrict__ Eq, unsigned short* __restrict__ qe_bf,
    unsigned short* __restrict__ qeT) {
  __shared__ unsigned short tile[64*264];
  int jc = blockIdx.x;
  int b  = blockIdx.y;
  int t = threadIdx.x;
  int jr = t >> 2, seg = (t & 3) * 64;
  size_t bL = (size_t)b * L_;
  int q = qs[bL + jc*64 + jr];
  {
    const float4* src = (const float4*)(Eq + (size_t)q*D_ + seg);
    float f[8];
    #pragma unroll
    for (int m = 0; m < 8; ++m) {
      float4 v0 = src[2*m], v1 = src[2*m+1];
      f[0]=v0.x; f[1]=v0.y; f[2]=v0.z; f[3]=v0.w;
      f[4]=v1.x; f[5]=v1.y; f[6]=v1.z; f[7]=v1.w;
      *(uint4*)&tile[jr*264 + seg + m*8] = pack8(f);
    }
  }
  __syncthreads();
  {
    unsigned short* dst = qe_bf + (bL + jc*64 + jr)*D_ + seg;
    #pragma unroll
    for (int m = 0; m < 8; ++m)
      *(uint4*)(dst + m*8) = *(const uint4*)&tile[jr*264 + seg + m*8];
  }
  {
    int d = t;
    union { unsigned short u[64]; uint4 v[8]; } row;
    #pragma unroll
    for (int j = 0; j < 64; ++j) row.u[j] = tile[j*264 + d];
    unsigned short* dst = qeT + ((size_t)b*D_ + d)*L_ + jc*64;
    #pragma unroll
    for (int m = 0; m < 8; ++m) *(uint4*)(dst + m*8) = row.v[m];
  }
}

// ---------------- K2: MFMA fused causal attention (v2) ---------------------
// sKT: compact 32-short rows + 16B-block XOR swizzle (block = m ^ ((row>>1)&3))
// -> conflict-free staging writes/reads at the b128 phase floor.
// LDS total 38.4 KB -> 4 blocks/CU co-resident (grid = exactly 4/CU).
#define KSTR 264
#define PSTR 40

__global__ __launch_bounds__(256, 4) void k_attn_mfma(
    const unsigned short* __restrict__ qe_bf, const unsigned short* __restrict__ qeT,
    const int* __restrict__ cs, unsigned short* __restrict__ attq,
    float* __restrict__ stv, float* __restrict__ s1v) {
  __shared__ unsigned short sK[32*KSTR];
  __shared__ unsigned short sKT[256*32];
  __shared__ unsigned short sP[64*PSTR];
  __shared__ float scj[32];
  __shared__ float redz[64], reds1[64], redzd[64];
  const int ord16[16] = {15,14,13,12, 8,9,10,11, 7,6,5,4, 0,1,2,3};
  int pos = blockIdx.x >> 6, b = blockIdx.x & 63;
  int t64 = ord16[pos];
  int i0 = t64 * 64;
  int t = threadIdx.x;
  int lane = t & 63, wv = t >> 6;
  int l15 = lane & 15, lq = lane >> 4;
  int koff = lq * 8;
  int swr = (l15 >> 1) & 3;              // read-side sKT block swizzle
  int swt = (t >> 1) & 3;                // write-side sKT block swizzle
  size_t bL = (size_t)b * L_;
  if (t < 64) { redz[t] = 0.f; reds1[t] = 0.f; redzd[t] = 0.f; }
  int mo = (wv & 1) * 16;
  int no = (wv >> 1) * 32;
  s16x8 qf[2][8];
  #pragma unroll
  for (int nt = 0; nt < 2; ++nt) {
    const unsigned short* qrow = qe_bf + (bL + i0 + no + nt*16 + l15)*D_;
    #pragma unroll
    for (int ks = 0; ks < 8; ++ks)
      qf[nt][ks] = *(const s16x8*)(qrow + ks*32 + koff);
  }
  int mo2 = (wv & 1) * 32;
  int do_ = (wv >> 1) * 128;
  f32x4 oacc[2][8];
  f32x4 zz = {0.f, 0.f, 0.f, 0.f};
  #pragma unroll
  for (int i = 0; i < 2; ++i)
    #pragma unroll
    for (int j = 0; j < 8; ++j) oacc[i][j] = zz;
  float rzs[2] = {0.f, 0.f}, rs1[2] = {0.f, 0.f}, rzd[2] = {0.f, 0.f};
  int njt = 2*t64 + 2;
  for (int jt = 0; jt < njt; ++jt) {
    int j0 = jt * 32;
    __syncthreads();   // prev PV reads of sKT/sP complete
    {  // stage sK [32][256] (padded rows, conflict-light)
      int jr = t >> 3, seg = (t & 7) * 32;
      const uint4* src = (const uint4*)(qe_bf + (bL + j0 + jr)*D_ + seg);
      #pragma unroll
      for (int m = 0; m < 4; ++m) *(uint4*)&sK[jr*KSTR + seg + m*8] = src[m];
    }
    {  // stage sKT [256][32], swizzled blocks
      const uint4* src = (const uint4*)(qeT + ((size_t)b*D_ + t)*L_ + j0);
      unsigned short* base = &sKT[t*32];
      #pragma unroll
      for (int m = 0; m < 4; ++m) *(uint4*)(base + ((m ^ swt)*8)) = src[m];
    }
    if (t < 32) scj[t] = (float)cs[bL + j0 + t];
    __syncthreads();
    // QK: S^T[j][i]
    f32x4 sacc[2]; sacc[0] = zz; sacc[1] = zz;
    #pragma unroll
    for (int ks = 0; ks < 8; ++ks) {
      s16x8 af = *(const s16x8*)&sK[(mo + l15)*KSTR + ks*32 + koff];
      sacc[0] = __builtin_amdgcn_mfma_f32_16x16x32_bf16(af, qf[0][ks], sacc[0], 0, 0, 0);
      sacc[1] = __builtin_amdgcn_mfma_f32_16x16x32_bf16(af, qf[1][ks], sacc[1], 0, 0, 0);
    }
    // exp + strict mask, reduce, write sP
    #pragma unroll
    for (int nt = 0; nt < 2; ++nt) {
      int ig = i0 + no + nt*16 + l15;
      union { unsigned short u[4]; unsigned long long q; } pk;
      #pragma unroll
      for (int r = 0; r < 4; ++r) {
        int jloc = mo + lq*4 + r;
        int jg = j0 + jloc;
        float ex = __expf(sacc[nt][r]);
        float e = (jg < ig) ? ex : 0.f;
        rzs[nt] += e;
        rs1[nt] = fmaf(e, scj[jloc], rs1[nt]);
        if (jg == ig) rzd[nt] += ex;
        pk.u[r] = f2bf(e);
      }
      *(unsigned long long*)&sP[(no + nt*16 + l15)*PSTR + mo + lq*4] = pk.q;
    }
    __syncthreads();
    // PV: O[i][d] += P[i][j] * V[j][d]
    s16x8 paf[2];
    #pragma unroll
    for (int mt = 0; mt < 2; ++mt)
      paf[mt] = *(const s16x8*)&sP[(mo2 + mt*16 + l15)*PSTR + koff];
    #pragma unroll
    for (int nt = 0; nt < 8; ++nt) {
      s16x8 bfr = *(const s16x8*)&sKT[(do_ + nt*16 + l15)*32 + ((lq ^ swr)*8)];
      oacc[0][nt] = __builtin_amdgcn_mfma_f32_16x16x32_bf16(paf[0], bfr, oacc[0][nt], 0, 0, 0);
      oacc[1][nt] = __builtin_amdgcn_mfma_f32_16x16x32_bf16(paf[1], bfr, oacc[1][nt], 0, 0, 0);
    }
  }
  #pragma unroll
  for (int nt = 0; nt < 2; ++nt) {
    float z = rzs[nt], s1 = rs1[nt], zd = rzd[nt];
    z  += __shfl_xor(z, 16);  z  += __shfl_xor(z, 32);
    s1 += __shfl_xor(s1, 16); s1 += __shfl_xor(s1, 32);
    zd += __shfl_xor(zd, 16); zd += __shfl_xor(zd, 32);
    if (lq == 0) {
      atomicAdd(&redz[no + nt*16 + l15], z);
      atomicAdd(&reds1[no + nt*16 + l15], s1);
      atomicAdd(&redzd[no + nt*16 + l15], zd);
    }
  }
  __syncthreads();
  if (t < 64) {
    float z = redz[t], zd = redzd[t], s1 = reds1[t];
    float inv = 1.0f / (z + 1e-8f*(z + zd));
    stv[bL + i0 + t] = z * inv;
    s1v[bL + i0 + t] = s1 * inv;
    redz[t] = inv;
  }
  __syncthreads();
  #pragma unroll
  for (int mt = 0; mt < 2; ++mt)
    #pragma unroll
    for (int r = 0; r < 4; ++r) {
      int iloc = mo2 + mt*16 + lq*4 + r;
      float inv = redz[iloc];
      size_t base = (bL + i0 + iloc)*D_ + do_;
      #pragma unroll
      for (int nt = 0; nt < 8; ++nt)
        attq[base + nt*16 + l15] = f2bf(oacc[mt][nt][r] * inv);
    }
}

// ------- MLP weight swizzle: frag order, A-side segments [qe|HRPq|cqc] -----
__global__ void k_cvt_sw(const float* __restrict__ W, unsigned short* __restrict__ Wf) {
  int tid = blockIdx.x*256 + threadIdx.x;      // 96 blocks: 384 frags x 64 lanes
  int lane = tid & 63;
  int frag = tid >> 6;
  int ks = frag % 24;
  int nt = frag / 24;
  int n = nt*16 + (lane & 15);
  int seg = ks >> 3;                           // 0,1,2
  int kor = (seg == 0 ? 0 : (seg == 1 ? 512 : 1024)) + (ks & 7)*32 + (lane >> 4)*8;
  const float4* src = (const float4*)(W + (size_t)n*1280 + kor);
  float f[8];
  float4 a = src[0], b = src[1];
  f[0]=a.x; f[1]=a.y; f[2]=a.z; f[3]=a.w; f[4]=b.x; f[5]=b.y; f[6]=b.z; f[7]=b.w;
  *(uint4*)(Wf + (size_t)frag*512 + (size_t)lane*8) = pack8(f);
}

// ------- conv weight swizzle: w[l][tap][ic][oc] -> frag order (linear k) ----
__global__ void k_cvt_convw_sw(const float* __restrict__ w,
                               unsigned short* __restrict__ wTf) {
  int tid = blockIdx.x*256 + threadIdx.x;      // 256 blocks/layer: 1024 frags
  int l = blockIdx.y;
  int lane = tid & 63;
  int frag = tid >> 6;
  int ks = frag & 31, nt = frag >> 5;
  int oc = nt*16 + (lane & 15);
  int k = ks*32 + (lane >> 4)*8;
  int tap = k >> 8, ic = k & 255;
  const float* src = w + (size_t)l*524288 + ((size_t)(tap*256 + ic))*512 + oc;
  float f[8];
  #pragma unroll
  for (int e = 0; e < 8; ++e) f[e] = src[(size_t)e*512];
  *(uint4*)(wTf + (size_t)l*524288 + (size_t)frag*512 + (size_t)lane*8) = pack8(f);
}

// ------- T/U tables: collapse ce & HRP-ce segments of H@W to per-col consts -
__global__ __launch_bounds__(256) void k_tu(const float* __restrict__ Ec,
    const float* __restrict__ W1w, const float* __restrict__ W2w,
    float* __restrict__ tu) {
  int n = blockIdx.x;
  int wv = threadIdx.x >> 6, lane = threadIdx.x & 63;
  int v = wv & 1;
  int reg = (wv >> 1) ? 768 : 256;
  const float* e  = Ec + (size_t)v*D_ + lane*4;
  const float* w1 = W1w + (size_t)n*1280 + reg + lane*4;
  const float* w2 = W2w + (size_t)n*1280 + reg + lane*4;
  float d1 = 0.f, d2 = 0.f;
  #pragma unroll
  for (int m = 0; m < 4; ++m) {
    float ev = e[m];
    d1 = fmaf(ev, w1[m], d1);
    d2 = fmaf(ev, w2[m], d2);
  }
  #pragma unroll
  for (int off = 32; off; off >>= 1) { d1 += __shfl_xor(d1, off); d2 += __shfl_xor(d2, off); }
  if (lane == 0) { tu[wv*256 + n] = d1; tu[1024 + wv*256 + n] = d2; }
}

// ---------------- K3: hybrid MFMA MLP (K=768) ------------------------------
__global__ __launch_bounds__(256, 2) void k_mlp_hyb(
    const unsigned short* __restrict__ qe_bf, const unsigned short* __restrict__ attq,
    const float* __restrict__ stv, const float* __restrict__ s1v,
    const int* __restrict__ cs, const float* __restrict__ cqc,
    const unsigned short* __restrict__ W1f, const float* __restrict__ W1b,
    const unsigned short* __restrict__ W2f, const float* __restrict__ W2b,
    const float* __restrict__ tu, unsigned short* __restrict__ out) {
  __shared__ unsigned short sA[2][4096];      // [buf][mt*64+lane][8] = 8KB each
  int t = threadIdx.x;
  int lane = t & 63, wv = t >> 6;
  int m0 = blockIdx.x * 128;
  int n0 = blockIdx.y * 128;
  int l15 = lane & 15, lq = lane >> 4;
  int lr = t >> 1, kh = (t & 1) * 16;
  int arow = m0 + lr;
  int sbase = ((lr >> 4)*64 + (kh >> 3)*16 + (lr & 15))*8;
  int ntb = (n0 >> 4) + wv*2;
  f32x4 acc1[8][2], acc2[8][2];
  f32x4 zz = {0.f, 0.f, 0.f, 0.f};
  #pragma unroll
  for (int i = 0; i < 8; ++i) { acc1[i][0]=zz; acc1[i][1]=zz; acc2[i][0]=zz; acc2[i][1]=zz; }

  auto stage_load = [&](int s, uint4* sr) {
    int ks = (s & 7)*32 + kh;
    if (s < 8) {
      const uint4* p = (const uint4*)(qe_bf + (size_t)arow*D_ + ks);
      sr[0] = p[0]; sr[1] = p[1];
    } else if (s < 16) {
      const uint4* p = (const uint4*)(attq + (size_t)arow*D_ + ks);
      sr[0] = p[0]; sr[1] = p[1];
    } else {
      const uint4* p = (const uint4*)(cqc + (size_t)arow*D_ + ks);  // 16 fp32
      sr[0] = p[0]; sr[1] = p[1]; sr[2] = p[2]; sr[3] = p[3];
    }
  };
  auto stage_write = [&](int s, const uint4* sr, int b) {
    unsigned short* dst = &sA[b][sbase];
    if (s < 16) {
      *(uint4*)dst = sr[0];
      *(uint4*)(dst + 128) = sr[1];
    } else {
      const float* f = (const float*)sr;
      *(uint4*)dst = pack8(f);
      *(uint4*)(dst + 128) = pack8(f + 8);
    }
  };
  auto loadB = [&](int s, s16x8* B1, s16x8* B2) {
    #pragma unroll
    for (int j = 0; j < 2; ++j) {
      size_t off = ((size_t)(ntb + j)*24 + s)*512 + (size_t)lane*8;
      B1[j] = *(const s16x8*)(W1f + off);
      B2[j] = *(const s16x8*)(W2f + off);
    }
  };

  uint4 sr[4];
  s16x8 bc1[2], bc2[2];
  stage_load(0, sr);
  stage_write(0, sr, 0);
  loadB(0, bc1, bc2);
  __syncthreads();
  for (int s = 0; s < 24; ++s) {
    int nxt = s + 1;
    uint4 srn[4];
    s16x8 bn1[2], bn2[2];
    if (nxt < 24) {
      loadB(nxt, bn1, bn2);
      stage_load(nxt, srn);
    }
    int cur = s & 1;
    s16x8 am[8];
    #pragma unroll
    for (int mt = 0; mt < 8; ++mt)
      am[mt] = *(const s16x8*)&sA[cur][(mt*64 + lane)*8];
    #pragma unroll
    for (int mt = 0; mt < 8; ++mt) {
      acc1[mt][0] = __builtin_amdgcn_mfma_f32_16x16x32_bf16(am[mt], bc1[0], acc1[mt][0], 0, 0, 0);
      acc1[mt][1] = __builtin_amdgcn_mfma_f32_16x16x32_bf16(am[mt], bc1[1], acc1[mt][1], 0, 0, 0);
      acc2[mt][0] = __builtin_amdgcn_mfma_f32_16x16x32_bf16(am[mt], bc2[0], acc2[mt][0], 0, 0, 0);
      acc2[mt][1] = __builtin_amdgcn_mfma_f32_16x16x32_bf16(am[mt], bc2[1], acc2[mt][1], 0, 0, 0);
    }
    if (nxt < 24) {
      stage_write(nxt, srn, cur ^ 1);
      bc1[0]=bn1[0]; bc1[1]=bn1[1]; bc2[0]=bn2[0]; bc2[1]=bn2[1];
    }
    __syncthreads();
  }
  // epilogue: + bias + (c? T1:T0) + s0*U0 + s1*U1, GLU
  int cols[2]; float cb1[2], cb2[2];
  float t1a[2], t1b[2], u1a[2], u1b[2], t2a[2], t2b[2], u2a[2], u2b[2];
  #pragma unroll
  for (int j = 0; j < 2; ++j) {
    int col = n0 + wv*32 + j*16 + l15;
    cols[j] = col;
    cb1[j] = W1b[col]; cb2[j] = W2b[col];
    t1a[j] = tu[col];       t1b[j] = tu[256+col];
    u1a[j] = tu[512+col];   u1b[j] = tu[768+col];
    t2a[j] = tu[1024+col];  t2b[j] = tu[1280+col];
    u2a[j] = tu[1536+col];  u2b[j] = tu[1792+col];
  }
  #pragma unroll
  for (int mt = 0; mt < 8; ++mt) {
    int rbase = m0 + mt*16 + lq*4;
    #pragma unroll
    for (int r = 0; r < 4; ++r) {
      int row = rbase + r;
      int c = cs[row];
      float s1r = s1v[row];
      float s0r = stv[row] - s1r;
      #pragma unroll
      for (int j = 0; j < 2; ++j) {
        float z1 = acc1[mt][j][r] + cb1[j] + (c ? t1b[j] : t1a[j]) + s0r*u1a[j] + s1r*u1b[j];
        float z2 = acc2[mt][j][r] + cb2[j] + (c ? t2b[j] : t2a[j]) + s0r*u2a[j] + s1r*u2b[j];
        out[(size_t)row*D_ + cols[j]] = f2bf(z1 * sigmoidf_(z2));
      }
    }
  }
}

// ---------------- K4: hybrid MFMA causal conv K=4 + GLU + residual ---------
__global__ __launch_bounds__(256, 2) void k_conv_hyb(
    const unsigned short* __restrict__ xin, const unsigned short* __restrict__ wTf,
    const float* __restrict__ bias, unsigned short* __restrict__ xout) {
  __shared__ unsigned short sA[2][4096];
  int t = threadIdx.x;
  int lane = t & 63, wv = t >> 6;
  int m0 = blockIdx.x * 128;
  int n0 = blockIdx.y * 128;
  int l15 = lane & 15, lq = lane >> 4;
  int lr = t >> 1, kh = (t & 1) * 16;
  int arow = m0 + lr;
  int al = arow & (L_ - 1);
  int sbase = ((lr >> 4)*64 + (kh >> 3)*16 + (lr & 15))*8;
  int nta = (n0 >> 4) + wv*2;
  f32x4 acca[8][2], accb[8][2];
  f32x4 zz = {0.f, 0.f, 0.f, 0.f};
  #pragma unroll
  for (int i = 0; i < 8; ++i) { acca[i][0]=zz; acca[i][1]=zz; accb[i][0]=zz; accb[i][1]=zz; }

  auto stage_load = [&](int s, uint4* sr) {
    int tap = s >> 3;
    uint4 z4 = {0,0,0,0};
    sr[0] = z4; sr[1] = z4;
    if (al + tap >= 3) {
      const uint4* p = (const uint4*)(xin + (size_t)(arow + tap - 3)*D_ + (s & 7)*32 + kh);
      sr[0] = p[0]; sr[1] = p[1];
    }
  };
  auto loadB = [&](int s, s16x8* Ba, s16x8* Bb) {
    #pragma unroll
    for (int j = 0; j < 2; ++j) {
      size_t off = ((size_t)(nta + j)*32 + s)*512 + (size_t)lane*8;
      Ba[j] = *(const s16x8*)(wTf + off);
      Bb[j] = *(const s16x8*)(wTf + off + 262144);   // b-half: +16 ntiles
    }
  };

  uint4 sr[2];
  s16x8 bca[2], bcb[2];
  stage_load(0, sr);
  { unsigned short* dst = &sA[0][sbase]; *(uint4*)dst = sr[0]; *(uint4*)(dst+128) = sr[1]; }
  loadB(0, bca, bcb);
  __syncthreads();
  for (int s = 0; s < 32; ++s) {
    int nxt = s + 1;
    uint4 srn[2];
    s16x8 bna[2], bnb[2];
    if (nxt < 32) {
      loadB(nxt, bna, bnb);
      stage_load(nxt, srn);
    }
    int cur = s & 1;
    s16x8 am[8];
    #pragma unroll
    for (int mt = 0; mt < 8; ++mt)
      am[mt] = *(const s16x8*)&sA[cur][(mt*64 + lane)*8];
    #pragma unroll
    for (int mt = 0; mt < 8; ++mt) {
      acca[mt][0] = __builtin_amdgcn_mfma_f32_16x16x32_bf16(am[mt], bca[0], acca[mt][0], 0, 0, 0);
      acca[mt][1] = __builtin_amdgcn_mfma_f32_16x16x32_bf16(am[mt], bca[1], acca[mt][1], 0, 0, 0);
      accb[mt][0] = __builtin_amdgcn_mfma_f32_16x16x32_bf16(am[mt], bcb[0], accb[mt][0], 0, 0, 0);
      accb[mt][1] = __builtin_amdgcn_mfma_f32_16x16x32_bf16(am[mt], bcb[1], accb[mt][1], 0, 0, 0);
    }
    if (nxt < 32) {
      unsigned short* dst = &sA[cur ^ 1][sbase];
      *(uint4*)dst = srn[0];
      *(uint4*)(dst + 128) = srn[1];
      bca[0]=bna[0]; bca[1]=bna[1]; bcb[0]=bnb[0]; bcb[1]=bnb[1];
    }
    __syncthreads();
  }
  #pragma unroll
  for (int j = 0; j < 2; ++j) {
    int col = n0 + wv*32 + j*16 + l15;
    float ba = bias[col], bb = bias[col + 256];
    #pragma unroll
    for (int mt = 0; mt < 8; ++mt) {
      int rbase = m0 + mt*16 + lq*4;
      #pragma unroll
      for (int r = 0; r < 4; ++r) {
        size_t off = (size_t)(rbase + r)*D_ + col;
        float za = acca[mt][j][r] + ba;
        float zb = accb[mt][j][r] + bb;
        float res = bf2f(xin[off]);
        xout[off] = f2bf(za * sigmoidf_(zb) + res);
      }
    }
  }
}

// ---------------- K5: predict = sigmoid(sum_d x*Eq[qs_next]) ---------------
__global__ void k_pred(const unsigned short* __restrict__ x, const int* __restrict__ qs,
                       const float* __restrict__ Eq, float* __restrict__ out) {
  int lane = threadIdx.x & 63;
  int wv = threadIdx.x >> 6;
  int oi = blockIdx.x*4 + wv;
  int b = oi / 1023;
  int tp = oi - b*1023;
  int row = b*L_ + tp;
  int q = qs[row + 1];
  ushort4 u = ((const ushort4*)(x + (size_t)row*D_))[lane];
  float4 qv = ((const float4*)(Eq + (size_t)q*D_))[lane];
  float s = bf2f(u.x)*qv.x + bf2f(u.y)*qv.y + bf2f(u.z)*qv.z + bf2f(u.w)*qv.w;
  #pragma unroll
  for (int off = 32; off; off >>= 1) s += __shfl_xor(s, off);
  if (lane == 0) out[oi] = sigmoidf_(s);
}

extern "C" void kernel_launch(void* const* d_in, const int* in_sizes, int n_in,
                              void* d_out, int out_size, void* d_ws, size_t ws_size,
                              hipStream_t stream) {
  const int*   qs  = (const int*)d_in[0];
  const int*   cs  = (const int*)d_in[1];
  const float* cqc = (const float*)d_in[2];
  const float* Eq  = (const float*)d_in[3];
  const float* Ec  = (const float*)d_in[4];
  const float* W1w = (const float*)d_in[5];
  const float* W1b = (const float*)d_in[6];
  const float* W2w = (const float*)d_in[7];
  const float* W2b = (const float*)d_in[8];
  const float* cw  = (const float*)d_in[9];
  const float* cb  = (const float*)d_in[10];
  float* out = (float*)d_out;

  // Workspace (MiB offsets), ~133 MiB with aliasing:
  //  [0,32)   qe_bf (dead after mlp)  -> xC
  //  [32,64)  qeT   (dead after attn) -> xB
  //  [64,96)  attq  (dead after mlp)  -> xD
  //  [96,128) xA (mlp out / conv1 in)
  //  [128,..) stv, s1v, W1f, W2f, wTf, tu
  char* w8 = (char*)d_ws;
  unsigned short* qe_bf = (unsigned short*)w8;
  unsigned short* qeT   = (unsigned short*)(w8 + ((size_t)32 << 20));
  unsigned short* attq  = (unsigned short*)(w8 + ((size_t)64 << 20));
  unsigned short* xA    = (unsigned short*)(w8 + ((size_t)96 << 20));
  float* stv = (float*)(w8 + ((size_t)128 << 20));
  float* s1v = stv + M_;
  unsigned short* W1f = (unsigned short*)(s1v + M_);
  unsigned short* W2f = W1f + 384*512;
  unsigned short* wTf = W2f + 384*512;           // 3 layers x 1024 frags x 512
  float* tu = (float*)(wTf + (size_t)3*524288);  // 2048 floats
  unsigned short* xB = qeT;
  unsigned short* xC = qe_bf;
  unsigned short* xD = attq;

  k_cvt_sw<<<96, 256, 0, stream>>>(W1w, W1f);
  k_cvt_sw<<<96, 256, 0, stream>>>(W2w, W2f);
  k_cvt_convw_sw<<<dim3(256, 3), 256, 0, stream>>>(cw, wTf);
  k_tu<<<256, 256, 0, stream>>>(Ec, W1w, W2w, tu);

  k_embedT<<<dim3(16, 64), 256, 0, stream>>>(qs, Eq, qe_bf, qeT);
  k_attn_mfma<<<1024, 256, 0, stream>>>(qe_bf, qeT, cs, attq, stv, s1v);
  k_mlp_hyb<<<dim3(M_/128, 2), 256, 0, stream>>>(qe_bf, attq, stv, s1v, cs, cqc,
                                                 W1f, W1b, W2f, W2b, tu, xA);
  k_conv_hyb<<<dim3(M_/128, 2), 256, 0, stream>>>(xA, wTf,           cb,        xB);
  k_conv_hyb<<<dim3(M_/128, 2), 256, 0, stream>>>(xB, wTf + 524288,  cb + 512,  xC);
  k_conv_hyb<<<dim3(M_/128, 2), 256, 0, stream>>>(xC, wTf + 1048576, cb + 1024, xD);
  k_pred<<<(B_*(L_-1))/4, 256, 0, stream>>>(xD, qs, Eq, out);
}

// Round 10
// 693.907 us; speedup vs baseline: 1.0964x; 1.0964x over previous
//
#include <hip/hip_runtime.h>
#include <hip/hip_bf16.h>

#define B_ 64
#define L_ 1024
#define D_ 256
#define M_ (B_*L_)

typedef __attribute__((ext_vector_type(8))) short s16x8;
typedef __attribute__((ext_vector_type(4))) float f32x4;

__device__ __forceinline__ float sigmoidf_(float z) { return 1.0f/(1.0f + __expf(-z)); }

__device__ __forceinline__ unsigned short f2bf(float x) {
  unsigned int u = __builtin_bit_cast(unsigned int, x);
  u += 0x7fffu + ((u >> 16) & 1u);          // RNE
  return (unsigned short)(u >> 16);
}
__device__ __forceinline__ float bf2f(unsigned short u) {
  unsigned int x = ((unsigned int)u) << 16;
  return __builtin_bit_cast(float, x);
}
__device__ __forceinline__ uint4 pack8(const float* f) {
  union { unsigned short u[8]; uint4 v; } r;
  #pragma unroll
  for (int i = 0; i < 8; ++i) r.u[i] = f2bf(f[i]);
  return r.v;
}

// ---------------- K1: gather+convert+transpose -----------------------------
__global__ __launch_bounds__(256) void k_embedT(const int* __restrict__ qs,
    const float* __restrict__ Eq, unsigned short* __restrict__ qe_bf,
    unsigned short* __restrict__ qeT) {
  __shared__ unsigned short tile[64*264];
  int jc = blockIdx.x;
  int b  = blockIdx.y;
  int t = threadIdx.x;
  int jr = t >> 2, seg = (t & 3) * 64;
  size_t bL = (size_t)b * L_;
  int q = qs[bL + jc*64 + jr];
  {
    const float4* src = (const float4*)(Eq + (size_t)q*D_ + seg);
    float f[8];
    #pragma unroll
    for (int m = 0; m < 8; ++m) {
      float4 v0 = src[2*m], v1 = src[2*m+1];
      f[0]=v0.x; f[1]=v0.y; f[2]=v0.z; f[3]=v0.w;
      f[4]=v1.x; f[5]=v1.y; f[6]=v1.z; f[7]=v1.w;
      *(uint4*)&tile[jr*264 + seg + m*8] = pack8(f);
    }
  }
  __syncthreads();
  {
    unsigned short* dst = qe_bf + (bL + jc*64 + jr)*D_ + seg;
    #pragma unroll
    for (int m = 0; m < 8; ++m)
      *(uint4*)(dst + m*8) = *(const uint4*)&tile[jr*264 + seg + m*8];
  }
  {
    int d = t;
    union { unsigned short u[64]; uint4 v[8]; } row;
    #pragma unroll
    for (int j = 0; j < 64; ++j) row.u[j] = tile[j*264 + d];
    unsigned short* dst = qeT + ((size_t)b*D_ + d)*L_ + jc*64;
    #pragma unroll
    for (int m = 0; m < 8; ++m) *(uint4*)(dst + m*8) = row.v[m];
  }
}

// ---------------- K2: MFMA fused causal attention (v3) ---------------------
// R8 structure + software-pipelined staging: next j-tile's qe/qeT/cs loads
// issue right after the QK-read barrier, land at next iteration's LDS write
// (latency spans QK+exp+PV+2 barriers). Compact swizzled sKT (verified R9).
// NO __launch_bounds__ min-waves: R9 showed it forces VGPR->64 + spills.
#define KSTR 264
#define PSTR 40

__global__ __launch_bounds__(256) void k_attn_mfma(
    const unsigned short* __restrict__ qe_bf, const unsigned short* __restrict__ qeT,
    const int* __restrict__ cs, unsigned short* __restrict__ attq,
    float* __restrict__ stv, float* __restrict__ s1v) {
  __shared__ unsigned short sK[32*KSTR];
  __shared__ unsigned short sKT[256*32];
  __shared__ unsigned short sP[64*PSTR];
  __shared__ float scj[32];
  __shared__ float redz[64], reds1[64], redzd[64];
  const int ord16[16] = {15,14,13,12, 8,9,10,11, 7,6,5,4, 0,1,2,3};
  int pos = blockIdx.x >> 6, b = blockIdx.x & 63;
  int t64 = ord16[pos];
  int i0 = t64 * 64;
  int t = threadIdx.x;
  int lane = t & 63, wv = t >> 6;
  int l15 = lane & 15, lq = lane >> 4;
  int koff = lq * 8;
  int swr = (l15 >> 1) & 3;              // read-side sKT block swizzle
  int swt = (t >> 1) & 3;                // write-side sKT block swizzle
  size_t bL = (size_t)b * L_;
  if (t < 64) { redz[t] = 0.f; reds1[t] = 0.f; redzd[t] = 0.f; }
  int mo = (wv & 1) * 16;
  int no = (wv >> 1) * 32;
  s16x8 qf[2][8];
  #pragma unroll
  for (int nt = 0; nt < 2; ++nt) {
    const unsigned short* qrow = qe_bf + (bL + i0 + no + nt*16 + l15)*D_;
    #pragma unroll
    for (int ks = 0; ks < 8; ++ks)
      qf[nt][ks] = *(const s16x8*)(qrow + ks*32 + koff);
  }
  int mo2 = (wv & 1) * 32;
  int do_ = (wv >> 1) * 128;
  f32x4 oacc[2][8];
  f32x4 zz = {0.f, 0.f, 0.f, 0.f};
  #pragma unroll
  for (int i = 0; i < 2; ++i)
    #pragma unroll
    for (int j = 0; j < 8; ++j) oacc[i][j] = zz;
  float rzs[2] = {0.f, 0.f}, rs1[2] = {0.f, 0.f}, rzd[2] = {0.f, 0.f};
  int njt = 2*t64 + 2;

  int jrK = t >> 3, segK = (t & 7) * 32;           // sK staging coords
  uint4 pk4[4], pt4[4];                            // staging prefetch regs
  float pscj;
  auto gload = [&](int j0) {
    const uint4* srcK = (const uint4*)(qe_bf + (bL + j0 + jrK)*D_ + segK);
    pk4[0] = srcK[0]; pk4[1] = srcK[1]; pk4[2] = srcK[2]; pk4[3] = srcK[3];
    const uint4* srcT = (const uint4*)(qeT + ((size_t)b*D_ + t)*L_ + j0);
    pt4[0] = srcT[0]; pt4[1] = srcT[1]; pt4[2] = srcT[2]; pt4[3] = srcT[3];
    pscj = (float)cs[bL + j0 + (t & 31)];
  };
  gload(0);
  for (int jt = 0; jt < njt; ++jt) {
    int j0 = jt * 32;
    __syncthreads();   // prev PV reads of sKT/sP complete (and init barrier)
    {  // write prefetched tile to LDS
      #pragma unroll
      for (int m = 0; m < 4; ++m) *(uint4*)&sK[jrK*KSTR + segK + m*8] = pk4[m];
      unsigned short* base = &sKT[t*32];
      #pragma unroll
      for (int m = 0; m < 4; ++m) *(uint4*)(base + ((m ^ swt)*8)) = pt4[m];
      if (t < 32) scj[t] = pscj;
    }
    __syncthreads();
    if (jt + 1 < njt) gload(j0 + 32);   // issue next loads; consumed next iter
    // QK: S^T[j][i]
    f32x4 sacc[2]; sacc[0] = zz; sacc[1] = zz;
    #pragma unroll
    for (int ks = 0; ks < 8; ++ks) {
      s16x8 af = *(const s16x8*)&sK[(mo + l15)*KSTR + ks*32 + koff];
      sacc[0] = __builtin_amdgcn_mfma_f32_16x16x32_bf16(af, qf[0][ks], sacc[0], 0, 0, 0);
      sacc[1] = __builtin_amdgcn_mfma_f32_16x16x32_bf16(af, qf[1][ks], sacc[1], 0, 0, 0);
    }
    // exp + strict mask, reduce, write sP
    #pragma unroll
    for (int nt = 0; nt < 2; ++nt) {
      int ig = i0 + no + nt*16 + l15;
      union { unsigned short u[4]; unsigned long long q; } pk;
      #pragma unroll
      for (int r = 0; r < 4; ++r) {
        int jloc = mo + lq*4 + r;
        int jg = j0 + jloc;
        float ex = __expf(sacc[nt][r]);
        float e = (jg < ig) ? ex : 0.f;
        rzs[nt] += e;
        rs1[nt] = fmaf(e, scj[jloc], rs1[nt]);
        if (jg == ig) rzd[nt] += ex;
        pk.u[r] = f2bf(e);
      }
      *(unsigned long long*)&sP[(no + nt*16 + l15)*PSTR + mo + lq*4] = pk.q;
    }
    __syncthreads();
    // PV: O[i][d] += P[i][j] * V[j][d]
    s16x8 paf[2];
    #pragma unroll
    for (int mt = 0; mt < 2; ++mt)
      paf[mt] = *(const s16x8*)&sP[(mo2 + mt*16 + l15)*PSTR + koff];
    #pragma unroll
    for (int nt = 0; nt < 8; ++nt) {
      s16x8 bfr = *(const s16x8*)&sKT[(do_ + nt*16 + l15)*32 + ((lq ^ swr)*8)];
      oacc[0][nt] = __builtin_amdgcn_mfma_f32_16x16x32_bf16(paf[0], bfr, oacc[0][nt], 0, 0, 0);
      oacc[1][nt] = __builtin_amdgcn_mfma_f32_16x16x32_bf16(paf[1], bfr, oacc[1][nt], 0, 0, 0);
    }
  }
  #pragma unroll
  for (int nt = 0; nt < 2; ++nt) {
    float z = rzs[nt], s1 = rs1[nt], zd = rzd[nt];
    z  += __shfl_xor(z, 16);  z  += __shfl_xor(z, 32);
    s1 += __shfl_xor(s1, 16); s1 += __shfl_xor(s1, 32);
    zd += __shfl_xor(zd, 16); zd += __shfl_xor(zd, 32);
    if (lq == 0) {
      atomicAdd(&redz[no + nt*16 + l15], z);
      atomicAdd(&reds1[no + nt*16 + l15], s1);
      atomicAdd(&redzd[no + nt*16 + l15], zd);
    }
  }
  __syncthreads();
  if (t < 64) {
    float z = redz[t], zd = redzd[t], s1 = reds1[t];
    float inv = 1.0f / (z + 1e-8f*(z + zd));
    stv[bL + i0 + t] = z * inv;
    s1v[bL + i0 + t] = s1 * inv;
    redz[t] = inv;
  }
  __syncthreads();
  #pragma unroll
  for (int mt = 0; mt < 2; ++mt)
    #pragma unroll
    for (int r = 0; r < 4; ++r) {
      int iloc = mo2 + mt*16 + lq*4 + r;
      float inv = redz[iloc];
      size_t base = (bL + i0 + iloc)*D_ + do_;
      #pragma unroll
      for (int nt = 0; nt < 8; ++nt)
        attq[base + nt*16 + l15] = f2bf(oacc[mt][nt][r] * inv);
    }
}

// ------- MLP weight swizzle: frag order, A-side segments [qe|HRPq|cqc] -----
__global__ void k_cvt_sw(const float* __restrict__ W, unsigned short* __restrict__ Wf) {
  int tid = blockIdx.x*256 + threadIdx.x;      // 96 blocks: 384 frags x 64 lanes
  int lane = tid & 63;
  int frag = tid >> 6;
  int ks = frag % 24;
  int nt = frag / 24;
  int n = nt*16 + (lane & 15);
  int seg = ks >> 3;                           // 0,1,2
  int kor = (seg == 0 ? 0 : (seg == 1 ? 512 : 1024)) + (ks & 7)*32 + (lane >> 4)*8;
  const float4* src = (const float4*)(W + (size_t)n*1280 + kor);
  float f[8];
  float4 a = src[0], b = src[1];
  f[0]=a.x; f[1]=a.y; f[2]=a.z; f[3]=a.w; f[4]=b.x; f[5]=b.y; f[6]=b.z; f[7]=b.w;
  *(uint4*)(Wf + (size_t)frag*512 + (size_t)lane*8) = pack8(f);
}

// ------- conv weight swizzle: w[l][tap][ic][oc] -> frag order (linear k) ----
__global__ void k_cvt_convw_sw(const float* __restrict__ w,
                               unsigned short* __restrict__ wTf) {
  int tid = blockIdx.x*256 + threadIdx.x;      // 256 blocks/layer: 1024 frags
  int l = blockIdx.y;
  int lane = tid & 63;
  int frag = tid >> 6;
  int ks = frag & 31, nt = frag >> 5;
  int oc = nt*16 + (lane & 15);
  int k = ks*32 + (lane >> 4)*8;
  int tap = k >> 8, ic = k & 255;
  const float* src = w + (size_t)l*524288 + ((size_t)(tap*256 + ic))*512 + oc;
  float f[8];
  #pragma unroll
  for (int e = 0; e < 8; ++e) f[e] = src[(size_t)e*512];
  *(uint4*)(wTf + (size_t)l*524288 + (size_t)frag*512 + (size_t)lane*8) = pack8(f);
}

// ------- T/U tables: collapse ce & HRP-ce segments of H@W to per-col consts -
__global__ __launch_bounds__(256) void k_tu(const float* __restrict__ Ec,
    const float* __restrict__ W1w, const float* __restrict__ W2w,
    float* __restrict__ tu) {
  int n = blockIdx.x;
  int wv = threadIdx.x >> 6, lane = threadIdx.x & 63;
  int v = wv & 1;
  int reg = (wv >> 1) ? 768 : 256;
  const float* e  = Ec + (size_t)v*D_ + lane*4;
  const float* w1 = W1w + (size_t)n*1280 + reg + lane*4;
  const float* w2 = W2w + (size_t)n*1280 + reg + lane*4;
  float d1 = 0.f, d2 = 0.f;
  #pragma unroll
  for (int m = 0; m < 4; ++m) {
    float ev = e[m];
    d1 = fmaf(ev, w1[m], d1);
    d2 = fmaf(ev, w2[m], d2);
  }
  #pragma unroll
  for (int off = 32; off; off >>= 1) { d1 += __shfl_xor(d1, off); d2 += __shfl_xor(d2, off); }
  if (lane == 0) { tu[wv*256 + n] = d1; tu[1024 + wv*256 + n] = d2; }
}

// ---------------- K3: hybrid MFMA MLP (K=768) ------------------------------
__global__ __launch_bounds__(256, 2) void k_mlp_hyb(
    const unsigned short* __restrict__ qe_bf, const unsigned short* __restrict__ attq,
    const float* __restrict__ stv, const float* __restrict__ s1v,
    const int* __restrict__ cs, const float* __restrict__ cqc,
    const unsigned short* __restrict__ W1f, const float* __restrict__ W1b,
    const unsigned short* __restrict__ W2f, const float* __restrict__ W2b,
    const float* __restrict__ tu, unsigned short* __restrict__ out) {
  __shared__ unsigned short sA[2][4096];      // [buf][mt*64+lane][8] = 8KB each
  int t = threadIdx.x;
  int lane = t & 63, wv = t >> 6;
  int m0 = blockIdx.x * 128;
  int n0 = blockIdx.y * 128;
  int l15 = lane & 15, lq = lane >> 4;
  int lr = t >> 1, kh = (t & 1) * 16;
  int arow = m0 + lr;
  int sbase = ((lr >> 4)*64 + (kh >> 3)*16 + (lr & 15))*8;
  int ntb = (n0 >> 4) + wv*2;
  f32x4 acc1[8][2], acc2[8][2];
  f32x4 zz = {0.f, 0.f, 0.f, 0.f};
  #pragma unroll
  for (int i = 0; i < 8; ++i) { acc1[i][0]=zz; acc1[i][1]=zz; acc2[i][0]=zz; acc2[i][1]=zz; }

  auto stage_load = [&](int s, uint4* sr) {
    int ks = (s & 7)*32 + kh;
    if (s < 8) {
      const uint4* p = (const uint4*)(qe_bf + (size_t)arow*D_ + ks);
      sr[0] = p[0]; sr[1] = p[1];
    } else if (s < 16) {
      const uint4* p = (const uint4*)(attq + (size_t)arow*D_ + ks);
      sr[0] = p[0]; sr[1] = p[1];
    } else {
      const uint4* p = (const uint4*)(cqc + (size_t)arow*D_ + ks);  // 16 fp32
      sr[0] = p[0]; sr[1] = p[1]; sr[2] = p[2]; sr[3] = p[3];
    }
  };
  auto stage_write = [&](int s, const uint4* sr, int b) {
    unsigned short* dst = &sA[b][sbase];
    if (s < 16) {
      *(uint4*)dst = sr[0];
      *(uint4*)(dst + 128) = sr[1];
    } else {
      const float* f = (const float*)sr;
      *(uint4*)dst = pack8(f);
      *(uint4*)(dst + 128) = pack8(f + 8);
    }
  };
  auto loadB = [&](int s, s16x8* B1, s16x8* B2) {
    #pragma unroll
    for (int j = 0; j < 2; ++j) {
      size_t off = ((size_t)(ntb + j)*24 + s)*512 + (size_t)lane*8;
      B1[j] = *(const s16x8*)(W1f + off);
      B2[j] = *(const s16x8*)(W2f + off);
    }
  };

  uint4 sr[4];
  s16x8 bc1[2], bc2[2];
  stage_load(0, sr);
  stage_write(0, sr, 0);
  loadB(0, bc1, bc2);
  __syncthreads();
  for (int s = 0; s < 24; ++s) {
    int nxt = s + 1;
    uint4 srn[4];
    s16x8 bn1[2], bn2[2];
    if (nxt < 24) {
      loadB(nxt, bn1, bn2);
      stage_load(nxt, srn);
    }
    int cur = s & 1;
    s16x8 am[8];
    #pragma unroll
    for (int mt = 0; mt < 8; ++mt)
      am[mt] = *(const s16x8*)&sA[cur][(mt*64 + lane)*8];
    #pragma unroll
    for (int mt = 0; mt < 8; ++mt) {
      acc1[mt][0] = __builtin_amdgcn_mfma_f32_16x16x32_bf16(am[mt], bc1[0], acc1[mt][0], 0, 0, 0);
      acc1[mt][1] = __builtin_amdgcn_mfma_f32_16x16x32_bf16(am[mt], bc1[1], acc1[mt][1], 0, 0, 0);
      acc2[mt][0] = __builtin_amdgcn_mfma_f32_16x16x32_bf16(am[mt], bc2[0], acc2[mt][0], 0, 0, 0);
      acc2[mt][1] = __builtin_amdgcn_mfma_f32_16x16x32_bf16(am[mt], bc2[1], acc2[mt][1], 0, 0, 0);
    }
    if (nxt < 24) {
      stage_write(nxt, srn, cur ^ 1);
      bc1[0]=bn1[0]; bc1[1]=bn1[1]; bc2[0]=bn2[0]; bc2[1]=bn2[1];
    }
    __syncthreads();
  }
  // epilogue: + bias + (c? T1:T0) + s0*U0 + s1*U1, GLU
  int cols[2]; float cb1[2], cb2[2];
  float t1a[2], t1b[2], u1a[2], u1b[2], t2a[2], t2b[2], u2a[2], u2b[2];
  #pragma unroll
  for (int j = 0; j < 2; ++j) {
    int col = n0 + wv*32 + j*16 + l15;
    cols[j] = col;
    cb1[j] = W1b[col]; cb2[j] = W2b[col];
    t1a[j] = tu[col];       t1b[j] = tu[256+col];
    u1a[j] = tu[512+col];   u1b[j] = tu[768+col];
    t2a[j] = tu[1024+col];  t2b[j] = tu[1280+col];
    u2a[j] = tu[1536+col];  u2b[j] = tu[1792+col];
  }
  #pragma unroll
  for (int mt = 0; mt < 8; ++mt) {
    int rbase = m0 + mt*16 + lq*4;
    #pragma unroll
    for (int r = 0; r < 4; ++r) {
      int row = rbase + r;
      int c = cs[row];
      float s1r = s1v[row];
      float s0r = stv[row] - s1r;
      #pragma unroll
      for (int j = 0; j < 2; ++j) {
        float z1 = acc1[mt][j][r] + cb1[j] + (c ? t1b[j] : t1a[j]) + s0r*u1a[j] + s1r*u1b[j];
        float z2 = acc2[mt][j][r] + cb2[j] + (c ? t2b[j] : t2a[j]) + s0r*u2a[j] + s1r*u2b[j];
        out[(size_t)row*D_ + cols[j]] = f2bf(z1 * sigmoidf_(z2));
      }
    }
  }
}

// ---------------- K4: hybrid MFMA causal conv K=4 + GLU + residual ---------
__global__ __launch_bounds__(256, 2) void k_conv_hyb(
    const unsigned short* __restrict__ xin, const unsigned short* __restrict__ wTf,
    const float* __restrict__ bias, unsigned short* __restrict__ xout) {
  __shared__ unsigned short sA[2][4096];
  int t = threadIdx.x;
  int lane = t & 63, wv = t >> 6;
  int m0 = blockIdx.x * 128;
  int n0 = blockIdx.y * 128;
  int l15 = lane & 15, lq = lane >> 4;
  int lr = t >> 1, kh = (t & 1) * 16;
  int arow = m0 + lr;
  int al = arow & (L_ - 1);
  int sbase = ((lr >> 4)*64 + (kh >> 3)*16 + (lr & 15))*8;
  int nta = (n0 >> 4) + wv*2;
  f32x4 acca[8][2], accb[8][2];
  f32x4 zz = {0.f, 0.f, 0.f, 0.f};
  #pragma unroll
  for (int i = 0; i < 8; ++i) { acca[i][0]=zz; acca[i][1]=zz; accb[i][0]=zz; accb[i][1]=zz; }

  auto stage_load = [&](int s, uint4* sr) {
    int tap = s >> 3;
    uint4 z4 = {0,0,0,0};
    sr[0] = z4; sr[1] = z4;
    if (al + tap >= 3) {
      const uint4* p = (const uint4*)(xin + (size_t)(arow + tap - 3)*D_ + (s & 7)*32 + kh);
      sr[0] = p[0]; sr[1] = p[1];
    }
  };
  auto loadB = [&](int s, s16x8* Ba, s16x8* Bb) {
    #pragma unroll
    for (int j = 0; j < 2; ++j) {
      size_t off = ((size_t)(nta + j)*32 + s)*512 + (size_t)lane*8;
      Ba[j] = *(const s16x8*)(wTf + off);
      Bb[j] = *(const s16x8*)(wTf + off + 262144);   // b-half: +16 ntiles
    }
  };

  uint4 sr[2];
  s16x8 bca[2], bcb[2];
  stage_load(0, sr);
  { unsigned short* dst = &sA[0][sbase]; *(uint4*)dst = sr[0]; *(uint4*)(dst+128) = sr[1]; }
  loadB(0, bca, bcb);
  __syncthreads();
  for (int s = 0; s < 32; ++s) {
    int nxt = s + 1;
    uint4 srn[2];
    s16x8 bna[2], bnb[2];
    if (nxt < 32) {
      loadB(nxt, bna, bnb);
      stage_load(nxt, srn);
    }
    int cur = s & 1;
    s16x8 am[8];
    #pragma unroll
    for (int mt = 0; mt < 8; ++mt)
      am[mt] = *(const s16x8*)&sA[cur][(mt*64 + lane)*8];
    #pragma unroll
    for (int mt = 0; mt < 8; ++mt) {
      acca[mt][0] = __builtin_amdgcn_mfma_f32_16x16x32_bf16(am[mt], bca[0], acca[mt][0], 0, 0, 0);
      acca[mt][1] = __builtin_amdgcn_mfma_f32_16x16x32_bf16(am[mt], bca[1], acca[mt][1], 0, 0, 0);
      accb[mt][0] = __builtin_amdgcn_mfma_f32_16x16x32_bf16(am[mt], bcb[0], accb[mt][0], 0, 0, 0);
      accb[mt][1] = __builtin_amdgcn_mfma_f32_16x16x32_bf16(am[mt], bcb[1], accb[mt][1], 0, 0, 0);
    }
    if (nxt < 32) {
      unsigned short* dst = &sA[cur ^ 1][sbase];
      *(uint4*)dst = srn[0];
      *(uint4*)(dst + 128) = srn[1];
      bca[0]=bna[0]; bca[1]=bna[1]; bcb[0]=bnb[0]; bcb[1]=bnb[1];
    }
    __syncthreads();
  }
  #pragma unroll
  for (int j = 0; j < 2; ++j) {
    int col = n0 + wv*32 + j*16 + l15;
    float ba = bias[col], bb = bias[col + 256];
    #pragma unroll
    for (int mt = 0; mt < 8; ++mt) {
      int rbase = m0 + mt*16 + lq*4;
      #pragma unroll
      for (int r = 0; r < 4; ++r) {
        size_t off = (size_t)(rbase + r)*D_ + col;
        float za = acca[mt][j][r] + ba;
        float zb = accb[mt][j][r] + bb;
        float res = bf2f(xin[off]);
        xout[off] = f2bf(za * sigmoidf_(zb) + res);
      }
    }
  }
}

// ---------------- K5: predict = sigmoid(sum_d x*Eq[qs_next]) ---------------
__global__ void k_pred(const unsigned short* __restrict__ x, const int* __restrict__ qs,
                       const float* __restrict__ Eq, float* __restrict__ out) {
  int lane = threadIdx.x & 63;
  int wv = threadIdx.x >> 6;
  int oi = blockIdx.x*4 + wv;
  int b = oi / 1023;
  int tp = oi - b*1023;
  int row = b*L_ + tp;
  int q = qs[row + 1];
  ushort4 u = ((const ushort4*)(x + (size_t)row*D_))[lane];
  float4 qv = ((const float4*)(Eq + (size_t)q*D_))[lane];
  float s = bf2f(u.x)*qv.x + bf2f(u.y)*qv.y + bf2f(u.z)*qv.z + bf2f(u.w)*qv.w;
  #pragma unroll
  for (int off = 32; off; off >>= 1) s += __shfl_xor(s, off);
  if (lane == 0) out[oi] = sigmoidf_(s);
}

extern "C" void kernel_launch(void* const* d_in, const int* in_sizes, int n_in,
                              void* d_out, int out_size, void* d_ws, size_t ws_size,
                              hipStream_t stream) {
  const int*   qs  = (const int*)d_in[0];
  const int*   cs  = (const int*)d_in[1];
  const float* cqc = (const float*)d_in[2];
  const float* Eq  = (const float*)d_in[3];
  const float* Ec  = (const float*)d_in[4];
  const float* W1w = (const float*)d_in[5];
  const float* W1b = (const float*)d_in[6];
  const float* W2w = (const float*)d_in[7];
  const float* W2b = (const float*)d_in[8];
  const float* cw  = (const float*)d_in[9];
  const float* cb  = (const float*)d_in[10];
  float* out = (float*)d_out;

  // Workspace (MiB offsets), ~133 MiB with aliasing:
  //  [0,32)   qe_bf (dead after mlp)  -> xC
  //  [32,64)  qeT   (dead after attn) -> xB
  //  [64,96)  attq  (dead after mlp)  -> xD
  //  [96,128) xA (mlp out / conv1 in)
  //  [128,..) stv, s1v, W1f, W2f, wTf, tu
  char* w8 = (char*)d_ws;
  unsigned short* qe_bf = (unsigned short*)w8;
  unsigned short* qeT   = (unsigned short*)(w8 + ((size_t)32 << 20));
  unsigned short* attq  = (unsigned short*)(w8 + ((size_t)64 << 20));
  unsigned short* xA    = (unsigned short*)(w8 + ((size_t)96 << 20));
  float* stv = (float*)(w8 + ((size_t)128 << 20));
  float* s1v = stv + M_;
  unsigned short* W1f = (unsigned short*)(s1v + M_);
  unsigned short* W2f = W1f + 384*512;
  unsigned short* wTf = W2f + 384*512;           // 3 layers x 1024 frags x 512
  float* tu = (float*)(wTf + (size_t)3*524288);  // 2048 floats
  unsigned short* xB = qeT;
  unsigned short* xC = qe_bf;
  unsigned short* xD = attq;

  k_cvt_sw<<<96, 256, 0, stream>>>(W1w, W1f);
  k_cvt_sw<<<96, 256, 0, stream>>>(W2w, W2f);
  k_cvt_convw_sw<<<dim3(256, 3), 256, 0, stream>>>(cw, wTf);
  k_tu<<<256, 256, 0, stream>>>(Ec, W1w, W2w, tu);

  k_embedT<<<dim3(16, 64), 256, 0, stream>>>(qs, Eq, qe_bf, qeT);
  k_attn_mfma<<<1024, 256, 0, stream>>>(qe_bf, qeT, cs, attq, stv, s1v);
  k_mlp_hyb<<<dim3(M_/128, 2), 256, 0, stream>>>(qe_bf, attq, stv, s1v, cs, cqc,
                                                 W1f, W1b, W2f, W2b, tu, xA);
  k_conv_hyb<<<dim3(M_/128, 2), 256, 0, stream>>>(xA, wTf,           cb,        xB);
  k_conv_hyb<<<dim3(M_/128, 2), 256, 0, stream>>>(xB, wTf + 524288,  cb + 512,  xC);
  k_conv_hyb<<<dim3(M_/128, 2), 256, 0, stream>>>(xC, wTf + 1048576, cb + 1024, xD);
  k_pred<<<(B_*(L_-1))/4, 256, 0, stream>>>(xD, qs, Eq, out);
}